// Round 1
// baseline (1348.228 us; speedup 1.0000x reference)
//
#include <hip/hip_runtime.h>

#define EPS 1e-5f
#define NB 1024      // batch
#define LX 8064      // input length
#define C  32        // channels
#define L1 8052      // conv1 out len (k=13,s=1)
#define L2 671       // conv2 out len (k=12,s=12)
#define L3 27        // conv3 out len (k=24,s=24)
#define NH 13        // n_half (gathered cols)

// ---- workspace layout (float offsets) ----
#define WS_BN1P 0        // [16][64]  bucketed sum/sumsq for bn1
#define WS_BN2P 1024     // [32][64]
#define WS_BN3P 3072     // [16][192] (96 sum + 96 sumsq)
#define WS_BN4P 6144     // [16][64]  per-block partials (no atomics)
#define WS_ZEROF 7168    // zero region end (floats)
#define WS_SC3  7168     // [96]
#define WS_SH3  7264     // [96]
#define WS_SC4  7360     // [32]
#define WS_SH4  7392     // [32]
#define WS_B2F  7424     // [32]  conv2 bias with bn1-shift folded
#define WS_B3F  7456     // [32]
#define WS_W2F  7488     // [32*32*12] conv2 weights * bn1-scale
#define WS_W3F  19776    // [32*32*24]
#define WS_FRAW 44352    // [1024*96] pooled features pre-bn3
#define WS_FC   142656   // [1024*32] relu(fc1) pre-bn4
#define WS_H2   175424   // [1024*32*671] relu(conv2) pre-bn2  (~84 MiB)
#define WS_TOTALF (WS_H2 + (size_t)NB * C * L2)

// ============================================================
// K1: conv1 + relu, accumulate per-channel sum/sumsq (bn1 stats).
// One block per sample; x row staged in LDS; 4 outputs per float4-window.
// ============================================================
__global__ __launch_bounds__(256) void k1_conv1_stats(
    const float* __restrict__ x, const float* __restrict__ w1,
    const float* __restrict__ b1, float* __restrict__ ws)
{
    __shared__ __align__(16) float xs[LX];
    __shared__ float red[2][C];
    const int n = blockIdx.x, t = threadIdx.x;
    for (int i = 4 * t; i < LX; i += 1024)
        *(float4*)&xs[i] = *(const float4*)&x[n * LX + i];
    if (t < 2 * C) ((float*)red)[t] = 0.f;
    __syncthreads();
    const int c = t & 31, g = t >> 5;
    float w[13];
#pragma unroll
    for (int k = 0; k < 13; ++k) w[k] = w1[c * 13 + k];
    const float bias = b1[c];
    float s = 0.f, ss = 0.f;
    for (int m = g; m < 2013; m += 8) {   // 8052 = 4*2013 outputs, 4 per iter
        const int p = 4 * m;
        float4 a0 = *(const float4*)&xs[p];
        float4 a1 = *(const float4*)&xs[p + 4];
        float4 a2 = *(const float4*)&xs[p + 8];
        float4 a3 = *(const float4*)&xs[p + 12];
        float xv[16] = {a0.x,a0.y,a0.z,a0.w, a1.x,a1.y,a1.z,a1.w,
                        a2.x,a2.y,a2.z,a2.w, a3.x,a3.y,a3.z,a3.w};
#pragma unroll
        for (int u = 0; u < 4; ++u) {
            float acc = bias;
#pragma unroll
            for (int k = 0; k < 13; ++k) acc = fmaf(w[k], xv[u + k], acc);
            acc = fmaxf(acc, 0.f);
            s += acc; ss = fmaf(acc, acc, ss);
        }
    }
    atomicAdd(&red[0][c], s);
    atomicAdd(&red[1][c], ss);
    __syncthreads();
    if (t < C) {
        const int bkt = n & 15;           // hash blocks into 16 buckets
        atomicAdd(&ws[WS_BN1P + bkt * 64 + t], red[0][t]);
        atomicAdd(&ws[WS_BN1P + bkt * 64 + 32 + t], red[1][t]);
    }
}

// ============================================================
// K2: reduce bn1 buckets -> scale/shift, fold into conv2 weights/bias.
// bn(relu(h1)) is affine per in-channel -> w2f[o,i,k]=w2*scale[i],
// b2f[o]=b2[o]+sum_{i,k} w2[o,i,k]*shift[i].
// ============================================================
__global__ __launch_bounds__(256) void k2_fold_bn1(
    const float* __restrict__ w2, const float* __restrict__ b2,
    const float* __restrict__ g1, const float* __restrict__ bb1,
    float* __restrict__ ws)
{
    __shared__ float sc[C], sh[C];
    const int t = threadIdx.x;
    if (t < C) {
        float s = 0.f, q = 0.f;
        for (int b = 0; b < 16; ++b) {
            s += ws[WS_BN1P + b * 64 + t];
            q += ws[WS_BN1P + b * 64 + 32 + t];
        }
        const float cnt = (float)NB * (float)L1;
        const float m = s / cnt;
        const float v = q / cnt - m * m;   // biased var (ddof=0), matches jnp.var
        const float scale = g1[t] / sqrtf(v + EPS);
        sc[t] = scale;
        sh[t] = bb1[t] - m * scale;
    }
    __syncthreads();
    for (int idx = t; idx < C * C * 12; idx += 256)
        ws[WS_W2F + idx] = w2[idx] * sc[(idx / 12) & 31];
    if (t < C) {
        float acc = b2[t];
        for (int i = 0; i < C; ++i) {
            float wsum = 0.f;
            const float* wr = w2 + t * 384 + i * 12;
#pragma unroll
            for (int k = 0; k < 12; ++k) wsum += wr[k];
            acc = fmaf(wsum, sh[i], acc);
        }
        ws[WS_B2F + t] = acc;
    }
}

// ============================================================
// K3: fused conv1(+relu) recompute -> conv2(+relu), bn2 stats.
// conv2 is k=12,s=12 (non-overlapping) so conv1 recompute is FLOP-neutral
// vs. materializing the 1.05 GB h1 tensor (saves ~2.1 GB HBM traffic).
// Tile: one sample x 32 conv2 outputs. LDS ~51 KB -> 3 blocks/CU.
// ============================================================
#define TL 32
#define PT (12 * TL)   // 384 h1 positions per tile

__global__ __launch_bounds__(256) void k3_conv12(
    const float* __restrict__ x, const float* __restrict__ w1,
    const float* __restrict__ b1, float* __restrict__ ws)
{
    __shared__ __align__(16) float h1s[C][PT];   // 48 KB
    __shared__ __align__(16) float xs[PT + 12];
    __shared__ float red[2][C];
    const int tile = blockIdx.x, n = blockIdx.y, t = threadIdx.x;
    const int l0 = tile * TL;
    const int nl = min(TL, L2 - l0);     // 32 (or 31 in last tile)
    const int np = nl * 12;
    const int p0 = l0 * 12;
    for (int i = 4 * t; i < np + 12; i += 1024)
        *(float4*)&xs[i] = *(const float4*)&x[n * LX + p0 + i];
    if (t < 2 * C) ((float*)red)[t] = 0.f;
    __syncthreads();
    // ---- stage A: h1s[c][p] = relu(conv1) for the tile's window ----
    {
        const int c = t & 31, g = t >> 5;
        float w[13];
#pragma unroll
        for (int k = 0; k < 13; ++k) w[k] = w1[c * 13 + k];
        const float bias = b1[c];
        for (int m = g; 4 * m < np; m += 8) {
            const int p = 4 * m;
            float4 a0 = *(const float4*)&xs[p];
            float4 a1 = *(const float4*)&xs[p + 4];
            float4 a2 = *(const float4*)&xs[p + 8];
            float4 a3 = *(const float4*)&xs[p + 12];
            float xv[16] = {a0.x,a0.y,a0.z,a0.w, a1.x,a1.y,a1.z,a1.w,
                            a2.x,a2.y,a2.z,a2.w, a3.x,a3.y,a3.z,a3.w};
            float h[4];
#pragma unroll
            for (int u = 0; u < 4; ++u) {
                float acc = bias;
#pragma unroll
                for (int k = 0; k < 13; ++k) acc = fmaf(w[k], xv[u + k], acc);
                h[u] = fmaxf(acc, 0.f);
            }
            *(float4*)&h1s[c][p] = make_float4(h[0], h[1], h[2], h[3]);
        }
    }
    __syncthreads();
    // ---- stage B: conv2 over folded weights; lanes 0..31 share o ->
    // weight loads are 2-address-per-wave broadcasts (L1-served float4s) ----
    const int lloc = t & 31, og = t >> 5;
    const float* __restrict__ w2f = ws + WS_W2F;
    float hv[4];
    {
        float acc[4];
#pragma unroll
        for (int j = 0; j < 4; ++j) acc[j] = ws[WS_B2F + og + 8 * j];
        if (lloc < nl) {
            for (int i = 0; i < C; ++i) {
                const float4* hp = (const float4*)&h1s[i][12 * lloc];
                const float4 h0 = hp[0], h1 = hp[1], h2 = hp[2];
#pragma unroll
                for (int j = 0; j < 4; ++j) {
                    const int o = og + 8 * j;
                    const float4* wp = (const float4*)(w2f + (o * C + i) * 12);
                    const float4 w0 = wp[0], w1v = wp[1], w2v = wp[2];
                    float a = acc[j];
                    a = fmaf(w0.x, h0.x, a);  a = fmaf(w0.y, h0.y, a);
                    a = fmaf(w0.z, h0.z, a);  a = fmaf(w0.w, h0.w, a);
                    a = fmaf(w1v.x, h1.x, a); a = fmaf(w1v.y, h1.y, a);
                    a = fmaf(w1v.z, h1.z, a); a = fmaf(w1v.w, h1.w, a);
                    a = fmaf(w2v.x, h2.x, a); a = fmaf(w2v.y, h2.y, a);
                    a = fmaf(w2v.z, h2.z, a); a = fmaf(w2v.w, h2.w, a);
                    acc[j] = a;
                }
            }
        }
#pragma unroll
        for (int j = 0; j < 4; ++j) {
            if (lloc < nl) {
                const float r = fmaxf(acc[j], 0.f);
                hv[j] = r;
                const int o = og + 8 * j;
                ws[WS_H2 + ((size_t)n * C + o) * L2 + l0 + lloc] = r;  // lanes -> contiguous l
            } else hv[j] = 0.f;
        }
    }
    // ---- bn2 stats: shuffle-reduce (lanes 0..31 of each group share o) ----
#pragma unroll
    for (int j = 0; j < 4; ++j) {
        float v = hv[j], q = hv[j] * hv[j];
#pragma unroll
        for (int m = 16; m >= 1; m >>= 1) {
            v += __shfl_xor(v, m, 32);
            q += __shfl_xor(q, m, 32);
        }
        if ((t & 31) == 0) {
            const int o = og + 8 * j;
            atomicAdd(&red[0][o], v);
            atomicAdd(&red[1][o], q);
        }
    }
    __syncthreads();
    if (t < C) {
        const int bkt = (tile + 21 * n) & 31;  // 32 buckets -> ~672 adds/address
        atomicAdd(&ws[WS_BN2P + bkt * 64 + t], red[0][t]);
        atomicAdd(&ws[WS_BN2P + bkt * 64 + 32 + t], red[1][t]);
    }
}

// ============================================================
// K4: reduce bn2 buckets, fold into conv3 weights/bias.
// ============================================================
__global__ __launch_bounds__(256) void k4_fold_bn2(
    const float* __restrict__ w3, const float* __restrict__ b3,
    const float* __restrict__ g2, const float* __restrict__ bb2,
    float* __restrict__ ws)
{
    __shared__ float sc[C], sh[C];
    const int t = threadIdx.x;
    if (t < C) {
        float s = 0.f, q = 0.f;
        for (int b = 0; b < 32; ++b) {
            s += ws[WS_BN2P + b * 64 + t];
            q += ws[WS_BN2P + b * 64 + 32 + t];
        }
        const float cnt = (float)NB * (float)L2;
        const float m = s / cnt;
        const float v = q / cnt - m * m;
        const float scale = g2[t] / sqrtf(v + EPS);
        sc[t] = scale;
        sh[t] = bb2[t] - m * scale;
    }
    __syncthreads();
    for (int idx = t; idx < C * C * 24; idx += 256)
        ws[WS_W3F + idx] = w3[idx] * sc[(idx / 24) & 31];
    if (t < C) {
        float acc = b3[t];
        for (int i = 0; i < C; ++i) {
            float wsum = 0.f;
            const float* wr = w3 + t * 768 + i * 24;
#pragma unroll
            for (int k = 0; k < 24; ++k) wsum += wr[k];
            acc = fmaf(wsum, sh[i], acc);
        }
        ws[WS_B3F + t] = acc;
    }
}

// ============================================================
// K5: conv3 (no relu!) + per-sample gather(perm_idx) + {mean,std(ddof=1),max}
// One block per sample; per in-channel i: stage h2 row + weight slice in LDS.
// Writes f_raw[n][96] and bucketed bn3 stats.
// ============================================================
__global__ __launch_bounds__(256) void k5_conv3_pool(
    const int* __restrict__ perm, float* __restrict__ ws)
{
    __shared__ __align__(16) float row[648];     // 27*24 used positions
    __shared__ __align__(16) float wsl[C * 24];  // w3f[:,i,:]
    __shared__ float h3s[C][L3];
    const int n = blockIdx.x, t = threadIdx.x;
    const float* __restrict__ h2n = ws + WS_H2 + (size_t)n * (C * L2);
    float acc[4] = {0.f, 0.f, 0.f, 0.f};
    for (int i = 0; i < C; ++i) {
        __syncthreads();  // protect previous iteration's LDS reads
        for (int idx = t; idx < 648; idx += 256) row[idx] = h2n[i * L2 + idx];
        for (int idx = t; idx < C * 24; idx += 256)
            wsl[idx] = ws[WS_W3F + (idx / 24) * 768 + i * 24 + (idx % 24)];
        __syncthreads();
#pragma unroll
        for (int jj = 0; jj < 4; ++jj) {
            const int idx = t + jj * 256;
            if (idx < C * L3) {
                const int c = idx / L3, tt = idx % L3;
                float a = acc[jj];
                const float* wr = &wsl[c * 24];
                const float* rr = &row[24 * tt];
#pragma unroll
                for (int k = 0; k < 24; ++k) a = fmaf(wr[k], rr[k], a);
                acc[jj] = a;
            }
        }
    }
    __syncthreads();
#pragma unroll
    for (int jj = 0; jj < 4; ++jj) {
        const int idx = t + jj * 256;
        if (idx < C * L3) {
            const int c = idx / L3, tt = idx % L3;
            h3s[c][tt] = acc[jj] + ws[WS_B3F + c];
        }
    }
    __syncthreads();
    if (t < C) {
        int pidx[NH];
#pragma unroll
        for (int j = 0; j < NH; ++j) pidx[j] = perm[n * NH + j];
        float vals[NH];
#pragma unroll
        for (int j = 0; j < NH; ++j) vals[j] = h3s[t][pidx[j]];
        float s = 0.f;
#pragma unroll
        for (int j = 0; j < NH; ++j) s += vals[j];
        const float mu = s * (1.f / 13.f);
        float va = 0.f;
#pragma unroll
        for (int j = 0; j < NH; ++j) { const float d = vals[j] - mu; va = fmaf(d, d, va); }
        const float sd = sqrtf(va * (1.f / 12.f));   // ddof=1
        float mx = vals[0];
#pragma unroll
        for (int j = 1; j < NH; ++j) mx = fmaxf(mx, vals[j]);
        float* fr = ws + WS_FRAW + n * 96;
        fr[t] = mu; fr[32 + t] = sd; fr[64 + t] = mx;
        const int bkt = n & 15;
        float* bp = ws + WS_BN3P + bkt * 192;
        atomicAdd(&bp[t], mu);
        atomicAdd(&bp[32 + t], sd);
        atomicAdd(&bp[64 + t], mx);
        atomicAdd(&bp[96 + t], mu * mu);
        atomicAdd(&bp[128 + t], sd * sd);
        atomicAdd(&bp[160 + t], mx * mx);
    }
}

// ============================================================
// K5b: bn3 scale/shift from buckets.
// ============================================================
__global__ __launch_bounds__(128) void k5b_bn3(
    const float* __restrict__ g3, const float* __restrict__ bb3,
    float* __restrict__ ws)
{
    const int t = threadIdx.x;
    if (t < 96) {
        float s = 0.f, q = 0.f;
        for (int b = 0; b < 16; ++b) {
            s += ws[WS_BN3P + b * 192 + t];
            q += ws[WS_BN3P + b * 192 + 96 + t];
        }
        const float m = s / 1024.f;
        const float v = q / 1024.f - m * m;
        const float scale = g3[t] / sqrtf(v + EPS);
        ws[WS_SC3 + t] = scale;
        ws[WS_SH3 + t] = bb3[t] - m * scale;
    }
}

// ============================================================
// K6: bn3 affine (on the fly) + fc1 + relu, bn4 partials per block.
// 16 blocks x 64 rows. fc1_w staged in LDS with +1 pad (bank-conflict-free).
// ============================================================
__global__ __launch_bounds__(256) void k6_fc1(
    const float* __restrict__ fw, const float* __restrict__ fb,
    float* __restrict__ ws)
{
    __shared__ float wl[C][97];
    __shared__ __align__(16) float fbn[64][96];
    __shared__ float red[2][C];
    const int b = blockIdx.x, t = threadIdx.x;
    const int n0 = b * 64;
    for (int idx = t; idx < C * 96; idx += 256) wl[idx / 96][idx % 96] = fw[idx];
    if (t < 2 * C) ((float*)red)[t] = 0.f;
    for (int idx = t; idx < 64 * 96; idx += 256) {
        const int r = idx / 96, j = idx % 96;
        fbn[r][j] = fmaf(ws[WS_FRAW + (n0 + r) * 96 + j], ws[WS_SC3 + j], ws[WS_SH3 + j]);
    }
    __syncthreads();
    const int o = t & 31, rg = t >> 5;
    const float bo = fb[o];
    float s = 0.f, ss = 0.f;
    for (int mI = 0; mI < 8; ++mI) {
        const int r = rg + 8 * mI;
        float a = bo;
#pragma unroll
        for (int j = 0; j < 96; ++j) a = fmaf(wl[o][j], fbn[r][j], a);
        a = fmaxf(a, 0.f);
        ws[WS_FC + (n0 + r) * C + o] = a;
        s += a; ss = fmaf(a, a, ss);
    }
    atomicAdd(&red[0][o], s);
    atomicAdd(&red[1][o], ss);
    __syncthreads();
    if (t < C) {
        ws[WS_BN4P + b * 64 + t] = red[0][t];       // direct partials, no atomics
        ws[WS_BN4P + b * 64 + 32 + t] = red[1][t];
    }
}

// ============================================================
// K6b: bn4 scale/shift.
// ============================================================
__global__ __launch_bounds__(64) void k6b_bn4(
    const float* __restrict__ g4, const float* __restrict__ bb4,
    float* __restrict__ ws)
{
    const int t = threadIdx.x;
    if (t < C) {
        float s = 0.f, q = 0.f;
        for (int b = 0; b < 16; ++b) {
            s += ws[WS_BN4P + b * 64 + t];
            q += ws[WS_BN4P + b * 64 + 32 + t];
        }
        const float m = s / 1024.f;
        const float v = q / 1024.f - m * m;
        const float scale = g4[t] / sqrtf(v + EPS);
        ws[WS_SC4 + t] = scale;
        ws[WS_SH4 + t] = bb4[t] - m * scale;
    }
}

// ============================================================
// K7: bn4 affine (on the fly) + x1 = A^T f4 (rank-1-update tiling over v)
// + out = [f4, x1] @ gcn_w^T + gcn_b.  16 blocks x 64 output rows.
// ============================================================
__global__ __launch_bounds__(256) void k7_gcn(
    const float* __restrict__ A, const float* __restrict__ gw,
    const float* __restrict__ gb, const float* __restrict__ ws,
    float* __restrict__ out)
{
    __shared__ float As[8][64];
    __shared__ float fs[8][C];
    __shared__ float gws[C][65];     // +1 pad: lanes read stride-65 -> no conflicts
    __shared__ float f4s[64][C];
    __shared__ float x1s[64][C];
    const int t = threadIdx.x;
    const int w0 = blockIdx.x * 64;
    const int c = t & 31, wg = t >> 5;
    const float scC = ws[WS_SC4 + c], shC = ws[WS_SH4 + c];
    for (int idx = t; idx < 2048; idx += 256) gws[idx >> 6][idx & 63] = gw[idx];
    for (int idx = t; idx < 2048; idx += 256) {
        const int r = idx >> 5;                       // idx&31 == c (stride 256)
        f4s[r][c] = fmaf(ws[WS_FC + (w0 + r) * C + c], scC, shC);
    }
    float acc[8] = {0, 0, 0, 0, 0, 0, 0, 0};
    for (int v0 = 0; v0 < NB; v0 += 8) {
        __syncthreads();
        {
            const int vv = t >> 6, wl = t & 63;
            As[vv][wl]     = A[(size_t)(v0 + vv) * NB + w0 + wl];
            As[vv + 4][wl] = A[(size_t)(v0 + vv + 4) * NB + w0 + wl];
        }
        {
            const int vv = t >> 5;
            fs[vv][c] = fmaf(ws[WS_FC + (v0 + vv) * C + c], scC, shC);
        }
        __syncthreads();
#pragma unroll
        for (int vv = 0; vv < 8; ++vv) {
            const float fv = fs[vv][c];
#pragma unroll
            for (int j = 0; j < 8; ++j)
                acc[j] = fmaf(As[vv][wg + 8 * j], fv, acc[j]);   // broadcast read
        }
    }
    __syncthreads();
#pragma unroll
    for (int j = 0; j < 8; ++j) x1s[wg + 8 * j][c] = acc[j];
    __syncthreads();
    const float gbv = gb[c];
#pragma unroll
    for (int j = 0; j < 8; ++j) {
        const int wl = wg + 8 * j;
        float a = gbv;
#pragma unroll
        for (int cc = 0; cc < C; ++cc) {
            a = fmaf(gws[c][cc],      f4s[wl][cc], a);
            a = fmaf(gws[c][32 + cc], x1s[wl][cc], a);
        }
        out[(w0 + wl) * C + c] = a;
    }
}

// ============================================================
extern "C" void kernel_launch(void* const* d_in, const int* in_sizes, int n_in,
                              void* d_out, int out_size, void* d_ws, size_t ws_size,
                              hipStream_t stream)
{
    (void)in_sizes; (void)n_in; (void)out_size;
    const float* x    = (const float*)d_in[0];
    const int*   perm = (const int*)  d_in[1];
    const float* A    = (const float*)d_in[2];
    const float* c1w  = (const float*)d_in[3];
    const float* c1b  = (const float*)d_in[4];
    const float* c2w  = (const float*)d_in[5];
    const float* c2b  = (const float*)d_in[6];
    const float* c3w  = (const float*)d_in[7];
    const float* c3b  = (const float*)d_in[8];
    const float* g1   = (const float*)d_in[9];
    const float* bb1  = (const float*)d_in[10];
    const float* g2   = (const float*)d_in[11];
    const float* bb2  = (const float*)d_in[12];
    const float* g3   = (const float*)d_in[13];
    const float* bb3  = (const float*)d_in[14];
    const float* g4   = (const float*)d_in[15];
    const float* bb4  = (const float*)d_in[16];
    const float* fw   = (const float*)d_in[17];
    const float* fb   = (const float*)d_in[18];
    const float* gw   = (const float*)d_in[19];
    const float* gb   = (const float*)d_in[20];
    float* ws  = (float*)d_ws;
    float* out = (float*)d_out;

    // Need ~84.6 MiB of workspace for relu(conv2) + folded weights + stats.
    if (ws_size < WS_TOTALF * sizeof(float)) return;  // loud validation failure

    hipMemsetAsync(d_ws, 0, WS_ZEROF * sizeof(float), stream);  // stat buckets
    k1_conv1_stats<<<dim3(NB), dim3(256), 0, stream>>>(x, c1w, c1b, ws);
    k2_fold_bn1  <<<dim3(1),  dim3(256), 0, stream>>>(c2w, c2b, g1, bb1, ws);
    k3_conv12    <<<dim3(21, NB), dim3(256), 0, stream>>>(x, c1w, c1b, ws);
    k4_fold_bn2  <<<dim3(1),  dim3(256), 0, stream>>>(c3w, c3b, g2, bb2, ws);
    k5_conv3_pool<<<dim3(NB), dim3(256), 0, stream>>>(perm, ws);
    k5b_bn3      <<<dim3(1),  dim3(128), 0, stream>>>(g3, bb3, ws);
    k6_fc1       <<<dim3(16), dim3(256), 0, stream>>>(fw, fb, ws);
    k6b_bn4      <<<dim3(1),  dim3(64),  0, stream>>>(g4, bb4, ws);
    k7_gcn       <<<dim3(16), dim3(256), 0, stream>>>(A, gw, gb, ws, out);
}

// Round 3
// 737.669 us; speedup vs baseline: 1.8277x; 1.8277x over previous
//
#include <hip/hip_runtime.h>

#define EPS 1e-5f
#define NB 1024      // batch
#define LX 8064      // input length
#define C  32        // channels
#define L1 8052      // conv1 out len (k=13,s=1)
#define L2 671       // conv2 out len (k=12,s=12)
#define L3 27        // conv3 out len (k=24,s=24)
#define NH 13        // n_half (gathered cols)

typedef short bf16x8 __attribute__((ext_vector_type(8)));
typedef float f32x4  __attribute__((ext_vector_type(4)));

// ---- workspace layout (float offsets) ----
#define WS_BN1P 0        // [16][64]  bucketed sum/sumsq for bn1
#define WS_BN2P 1024     // [32][64]
#define WS_BN3P 3072     // [16][192] (96 sum + 96 sumsq)
#define WS_BN4P 6144     // [16][64]  per-block partials (no atomics)
#define WS_ZEROF 7168    // zero region end (floats)
#define WS_SC3  7168     // [96]
#define WS_SH3  7264     // [96]
#define WS_SC4  7360     // [32]
#define WS_SH4  7392     // [32]
#define WS_B2F  7424     // [32]  conv2 bias with bn1-shift folded
#define WS_B3F  7456     // [32]
#define WS_W2B  7488     // ushort region: hi[32][384] then lo[32][384] (12288 floats)
#define WS_W3F  19776    // [32*32*24] conv3 weights * bn2-scale (fp32)
#define WS_FRAW 44352    // [1024*96] pooled features pre-bn3
#define WS_FC   142656   // [1024*32] relu(fc1) pre-bn4
#define WS_H2   175424   // [1024*32*671] relu(conv2) pre-bn2  (~84 MiB)
#define WS_TOTALF (WS_H2 + (size_t)NB * C * L2)

static __device__ __forceinline__ unsigned short f2bf(float x) {
    union { float f; unsigned u; } v; v.f = x;
    unsigned r = (v.u + 0x7FFFu + ((v.u >> 16) & 1u)) >> 16;   // RNE
    return (unsigned short)r;
}
static __device__ __forceinline__ float bf2f(unsigned short h) {
    union { unsigned u; float f; } v; v.u = ((unsigned)h) << 16;
    return v.f;
}

// ============================================================
// K1: conv1 + relu, accumulate per-channel sum/sumsq (bn1 stats).
// ============================================================
__global__ __launch_bounds__(256) void k1_conv1_stats(
    const float* __restrict__ x, const float* __restrict__ w1,
    const float* __restrict__ b1, float* __restrict__ ws)
{
    __shared__ __align__(16) float xs[LX];
    __shared__ float red[2][C];
    const int n = blockIdx.x, t = threadIdx.x;
    for (int i = 4 * t; i < LX; i += 1024)
        *(float4*)&xs[i] = *(const float4*)&x[n * LX + i];
    if (t < 2 * C) ((float*)red)[t] = 0.f;
    __syncthreads();
    const int c = t & 31, g = t >> 5;
    float w[13];
#pragma unroll
    for (int k = 0; k < 13; ++k) w[k] = w1[c * 13 + k];
    const float bias = b1[c];
    float s = 0.f, ss = 0.f;
    for (int m = g; m < 2013; m += 8) {
        const int p = 4 * m;
        float4 a0 = *(const float4*)&xs[p];
        float4 a1 = *(const float4*)&xs[p + 4];
        float4 a2 = *(const float4*)&xs[p + 8];
        float4 a3 = *(const float4*)&xs[p + 12];
        float xv[16] = {a0.x,a0.y,a0.z,a0.w, a1.x,a1.y,a1.z,a1.w,
                        a2.x,a2.y,a2.z,a2.w, a3.x,a3.y,a3.z,a3.w};
#pragma unroll
        for (int u = 0; u < 4; ++u) {
            float acc = bias;
#pragma unroll
            for (int k = 0; k < 13; ++k) acc = fmaf(w[k], xv[u + k], acc);
            acc = fmaxf(acc, 0.f);
            s += acc; ss = fmaf(acc, acc, ss);
        }
    }
    atomicAdd(&red[0][c], s);
    atomicAdd(&red[1][c], ss);
    __syncthreads();
    if (t < C) {
        const int bkt = n & 15;
        atomicAdd(&ws[WS_BN1P + bkt * 64 + t], red[0][t]);
        atomicAdd(&ws[WS_BN1P + bkt * 64 + 32 + t], red[1][t]);
    }
}

// ============================================================
// K2: reduce bn1 buckets -> scale/shift; fold into conv2 weights as
// bf16 hi/lo pairs, layout [o][i*12+k] (matches w2's own ordering).
// ============================================================
__global__ __launch_bounds__(256) void k2_fold_bn1(
    const float* __restrict__ w2, const float* __restrict__ b2,
    const float* __restrict__ g1, const float* __restrict__ bb1,
    float* __restrict__ ws)
{
    __shared__ float sc[C], sh[C];
    const int t = threadIdx.x;
    if (t < C) {
        float s = 0.f, q = 0.f;
        for (int b = 0; b < 16; ++b) {
            s += ws[WS_BN1P + b * 64 + t];
            q += ws[WS_BN1P + b * 64 + 32 + t];
        }
        const float cnt = (float)NB * (float)L1;
        const float m = s / cnt;
        const float v = q / cnt - m * m;   // biased var, matches jnp.var
        const float scale = g1[t] / sqrtf(v + EPS);
        sc[t] = scale;
        sh[t] = bb1[t] - m * scale;
    }
    __syncthreads();
    unsigned short* __restrict__ w2b = (unsigned short*)(ws + WS_W2B);
    for (int idx = t; idx < C * C * 12; idx += 256) {
        const float wf = w2[idx] * sc[(idx / 12) & 31];
        const unsigned short hi = f2bf(wf);
        const unsigned short lo = f2bf(wf - bf2f(hi));
        w2b[idx] = hi;
        w2b[C * C * 12 + idx] = lo;
    }
    if (t < C) {
        float acc = b2[t];
        for (int i = 0; i < C; ++i) {
            float wsum = 0.f;
            const float* wr = w2 + t * 384 + i * 12;
#pragma unroll
            for (int k = 0; k < 12; ++k) wsum += wr[k];
            acc = fmaf(wsum, sh[i], acc);
        }
        ws[WS_B2F + t] = acc;
    }
}

// ============================================================
// K3: fused conv1(+relu) recompute (fp32, VALU) -> conv2 via bf16x3 MFMA.
// Stage A stores h1 as bf16 hi/lo in [l][k=i*12+kk] layout, row stride 392
// (byte-stride/16 = 49, odd -> conflict-free b128 A-fragment reads; the
// hi/lo b64 staging writes land <=2-way). Stage B: 4 waves, one 16x16
// (l x o) quadrant each; K=384 -> 12 steps x 3 MFMA (hi*hi+hi*lo+lo*hi).
// D layout (m89-verified): o = lane&15 + ohalf, l = lhalf + (lane>>4)*4 + r
// -> each lane's 4 outputs are l-contiguous (coalesced-ish stores),
// bn2 stats via shfl_xor(16,32) reduction over lanes sharing o.
// ============================================================
#define TL 32
#define PT (12 * TL)   // 384 h1 positions per tile
#define AS 392         // padded row stride (bf16 units)

__global__ __launch_bounds__(256) void k3_conv12(
    const float* __restrict__ x, const float* __restrict__ w1,
    const float* __restrict__ b1, float* __restrict__ ws)
{
    __shared__ __align__(16) unsigned short h1hi[TL][AS];   // 25088 B
    __shared__ __align__(16) unsigned short h1lo[TL][AS];   // 25088 B
    __shared__ __align__(16) float xs[PT + 12];
    __shared__ float red[2][C];
    const int tile = blockIdx.x, n = blockIdx.y, t = threadIdx.x;
    const int l0 = tile * TL;
    const int nl = min(TL, L2 - l0);     // 32 (31 in last tile)
    const int np = nl * 12;
    const int p0 = l0 * 12;
    for (int i = 4 * t; i < np + 12; i += 1024)
        *(float4*)&xs[i] = *(const float4*)&x[n * LX + p0 + i];
    if (nl < TL) {   // zero the tail row so stage B reads defined data
        for (int idx = t; idx < AS; idx += 256) {
            h1hi[TL - 1][idx] = 0;
            h1lo[TL - 1][idx] = 0;
        }
    }
    if (t < 2 * C) ((float*)red)[t] = 0.f;
    __syncthreads();
    // ---- stage A: conv1 + relu -> bf16 hi/lo into [l][c*12+kk] ----
    {
        const int c = t & 31, g = t >> 5;
        float w[13];
#pragma unroll
        for (int k = 0; k < 13; ++k) w[k] = w1[c * 13 + k];
        const float bias = b1[c];
        for (int m = g; 4 * m < np; m += 8) {
            const int p = 4 * m;                 // p%12 is always 0,4,8
            float4 a0 = *(const float4*)&xs[p];
            float4 a1 = *(const float4*)&xs[p + 4];
            float4 a2 = *(const float4*)&xs[p + 8];
            float4 a3 = *(const float4*)&xs[p + 12];
            float xv[16] = {a0.x,a0.y,a0.z,a0.w, a1.x,a1.y,a1.z,a1.w,
                            a2.x,a2.y,a2.z,a2.w, a3.x,a3.y,a3.z,a3.w};
            ushort4 hi4, lo4;
            float h[4];
#pragma unroll
            for (int u = 0; u < 4; ++u) {
                float acc = bias;
#pragma unroll
                for (int k = 0; k < 13; ++k) acc = fmaf(w[k], xv[u + k], acc);
                h[u] = fmaxf(acc, 0.f);
            }
            hi4.x = f2bf(h[0]); hi4.y = f2bf(h[1]);
            hi4.z = f2bf(h[2]); hi4.w = f2bf(h[3]);
            lo4.x = f2bf(h[0] - bf2f(hi4.x));
            lo4.y = f2bf(h[1] - bf2f(hi4.y));
            lo4.z = f2bf(h[2] - bf2f(hi4.z));
            lo4.w = f2bf(h[3] - bf2f(hi4.w));
            const int l = p / 12, kk0 = p - l * 12;
            const int off = c * 12 + kk0;
            *(ushort4*)&h1hi[l][off] = hi4;
            *(ushort4*)&h1lo[l][off] = lo4;
        }
    }
    __syncthreads();
    // ---- stage B: 3-term bf16 MFMA GEMM [32l x 384k] x [384k x 32o] ----
    {
        const int wv = t >> 6, lane = t & 63;
        const int m15 = lane & 15, kg = lane >> 4;
        const int lh = (wv >> 1) << 4, oh = (wv & 1) << 4;
        const int o = oh + m15;
        const unsigned short* __restrict__ w2b = (const unsigned short*)(ws + WS_W2B);
        const unsigned short* __restrict__ wh = w2b + o * 384 + kg * 8;
        const unsigned short* __restrict__ wl = wh + C * C * 12;
        const unsigned short* __restrict__ ah = &h1hi[lh + m15][kg * 8];
        const unsigned short* __restrict__ al = &h1lo[lh + m15][kg * 8];
        const float bias = ws[WS_B2F + o];
        f32x4 acc = {bias, bias, bias, bias};
#pragma unroll
        for (int kk = 0; kk < 12; ++kk) {
            const bf16x8 ahi = *(const bf16x8*)(ah + kk * 32);
            const bf16x8 alo = *(const bf16x8*)(al + kk * 32);
            const bf16x8 bhi = *(const bf16x8*)(wh + kk * 32);
            const bf16x8 blo = *(const bf16x8*)(wl + kk * 32);
            acc = __builtin_amdgcn_mfma_f32_16x16x32_bf16(ahi, bhi, acc, 0, 0, 0);
            acc = __builtin_amdgcn_mfma_f32_16x16x32_bf16(ahi, blo, acc, 0, 0, 0);
            acc = __builtin_amdgcn_mfma_f32_16x16x32_bf16(alo, bhi, acc, 0, 0, 0);
        }
        // relu + store + bn2 stat partials
        const int lbase = lh + kg * 4;
        float* __restrict__ hp = ws + WS_H2 + ((size_t)(n * C + o)) * L2 + l0 + lbase;
        float s = 0.f, ss = 0.f;
#pragma unroll
        for (int r = 0; r < 4; ++r) {
            const float v = fmaxf(acc[r], 0.f);
            if (lbase + r < nl) {
                hp[r] = v;
                s += v; ss = fmaf(v, v, ss);
            }
        }
        s  += __shfl_xor(s, 16);  s  += __shfl_xor(s, 32);
        ss += __shfl_xor(ss, 16); ss += __shfl_xor(ss, 32);
        if (kg == 0) {
            atomicAdd(&red[0][o], s);
            atomicAdd(&red[1][o], ss);
        }
    }
    __syncthreads();
    if (t < C) {
        const int bkt = (tile + 21 * n) & 31;
        atomicAdd(&ws[WS_BN2P + bkt * 64 + t], red[0][t]);
        atomicAdd(&ws[WS_BN2P + bkt * 64 + 32 + t], red[1][t]);
    }
}

// ============================================================
// K4: reduce bn2 buckets, fold into conv3 weights/bias (fp32).
// ============================================================
__global__ __launch_bounds__(256) void k4_fold_bn2(
    const float* __restrict__ w3, const float* __restrict__ b3,
    const float* __restrict__ g2, const float* __restrict__ bb2,
    float* __restrict__ ws)
{
    __shared__ float sc[C], sh[C];
    const int t = threadIdx.x;
    if (t < C) {
        float s = 0.f, q = 0.f;
        for (int b = 0; b < 32; ++b) {
            s += ws[WS_BN2P + b * 64 + t];
            q += ws[WS_BN2P + b * 64 + 32 + t];
        }
        const float cnt = (float)NB * (float)L2;
        const float m = s / cnt;
        const float v = q / cnt - m * m;
        const float scale = g2[t] / sqrtf(v + EPS);
        sc[t] = scale;
        sh[t] = bb2[t] - m * scale;
    }
    __syncthreads();
    for (int idx = t; idx < C * C * 24; idx += 256)
        ws[WS_W3F + idx] = w3[idx] * sc[(idx / 24) & 31];
    if (t < C) {
        float acc = b3[t];
        for (int i = 0; i < C; ++i) {
            float wsum = 0.f;
            const float* wr = w3 + t * 768 + i * 24;
#pragma unroll
            for (int k = 0; k < 24; ++k) wsum += wr[k];
            acc = fmaf(wsum, sh[i], acc);
        }
        ws[WS_B3F + t] = acc;
    }
}

// ============================================================
// K5: conv3 + per-sample gather(perm_idx) + {mean,std(ddof=1),max}.
// ============================================================
__global__ __launch_bounds__(256) void k5_conv3_pool(
    const int* __restrict__ perm, float* __restrict__ ws)
{
    __shared__ __align__(16) float row[648];
    __shared__ __align__(16) float wsl[C * 24];
    __shared__ float h3s[C][L3];
    const int n = blockIdx.x, t = threadIdx.x;
    const float* __restrict__ h2n = ws + WS_H2 + (size_t)n * (C * L2);
    float acc[4] = {0.f, 0.f, 0.f, 0.f};
    for (int i = 0; i < C; ++i) {
        __syncthreads();
        for (int idx = t; idx < 648; idx += 256) row[idx] = h2n[i * L2 + idx];
        for (int idx = t; idx < C * 24; idx += 256)
            wsl[idx] = ws[WS_W3F + (idx / 24) * 768 + i * 24 + (idx % 24)];
        __syncthreads();
#pragma unroll
        for (int jj = 0; jj < 4; ++jj) {
            const int idx = t + jj * 256;
            if (idx < C * L3) {
                const int c = idx / L3, tt = idx % L3;
                float a = acc[jj];
                const float* wr = &wsl[c * 24];
                const float* rr = &row[24 * tt];
#pragma unroll
                for (int k = 0; k < 24; ++k) a = fmaf(wr[k], rr[k], a);
                acc[jj] = a;
            }
        }
    }
    __syncthreads();
#pragma unroll
    for (int jj = 0; jj < 4; ++jj) {
        const int idx = t + jj * 256;
        if (idx < C * L3) {
            const int c = idx / L3, tt = idx % L3;
            h3s[c][tt] = acc[jj] + ws[WS_B3F + c];
        }
    }
    __syncthreads();
    if (t < C) {
        int pidx[NH];
#pragma unroll
        for (int j = 0; j < NH; ++j) pidx[j] = perm[n * NH + j];
        float vals[NH];
#pragma unroll
        for (int j = 0; j < NH; ++j) vals[j] = h3s[t][pidx[j]];
        float s = 0.f;
#pragma unroll
        for (int j = 0; j < NH; ++j) s += vals[j];
        const float mu = s * (1.f / 13.f);
        float va = 0.f;
#pragma unroll
        for (int j = 0; j < NH; ++j) { const float d = vals[j] - mu; va = fmaf(d, d, va); }
        const float sd = sqrtf(va * (1.f / 12.f));
        float mx = vals[0];
#pragma unroll
        for (int j = 1; j < NH; ++j) mx = fmaxf(mx, vals[j]);
        float* fr = ws + WS_FRAW + n * 96;
        fr[t] = mu; fr[32 + t] = sd; fr[64 + t] = mx;
        const int bkt = n & 15;
        float* bp = ws + WS_BN3P + bkt * 192;
        atomicAdd(&bp[t], mu);
        atomicAdd(&bp[32 + t], sd);
        atomicAdd(&bp[64 + t], mx);
        atomicAdd(&bp[96 + t], mu * mu);
        atomicAdd(&bp[128 + t], sd * sd);
        atomicAdd(&bp[160 + t], mx * mx);
    }
}

// ============================================================
// K5b: bn3 scale/shift from buckets.
// ============================================================
__global__ __launch_bounds__(128) void k5b_bn3(
    const float* __restrict__ g3, const float* __restrict__ bb3,
    float* __restrict__ ws)
{
    const int t = threadIdx.x;
    if (t < 96) {
        float s = 0.f, q = 0.f;
        for (int b = 0; b < 16; ++b) {
            s += ws[WS_BN3P + b * 192 + t];
            q += ws[WS_BN3P + b * 192 + 96 + t];
        }
        const float m = s / 1024.f;
        const float v = q / 1024.f - m * m;
        const float scale = g3[t] / sqrtf(v + EPS);
        ws[WS_SC3 + t] = scale;
        ws[WS_SH3 + t] = bb3[t] - m * scale;
    }
}

// ============================================================
// K6: bn3 affine + fc1 + relu, bn4 per-block partials.
// ============================================================
__global__ __launch_bounds__(256) void k6_fc1(
    const float* __restrict__ fw, const float* __restrict__ fb,
    float* __restrict__ ws)
{
    __shared__ float wl[C][97];
    __shared__ __align__(16) float fbn[64][96];
    __shared__ float red[2][C];
    const int b = blockIdx.x, t = threadIdx.x;
    const int n0 = b * 64;
    for (int idx = t; idx < C * 96; idx += 256) wl[idx / 96][idx % 96] = fw[idx];
    if (t < 2 * C) ((float*)red)[t] = 0.f;
    for (int idx = t; idx < 64 * 96; idx += 256) {
        const int r = idx / 96, j = idx % 96;
        fbn[r][j] = fmaf(ws[WS_FRAW + (n0 + r) * 96 + j], ws[WS_SC3 + j], ws[WS_SH3 + j]);
    }
    __syncthreads();
    const int o = t & 31, rg = t >> 5;
    const float bo = fb[o];
    float s = 0.f, ss = 0.f;
    for (int mI = 0; mI < 8; ++mI) {
        const int r = rg + 8 * mI;
        float a = bo;
#pragma unroll
        for (int j = 0; j < 96; ++j) a = fmaf(wl[o][j], fbn[r][j], a);
        a = fmaxf(a, 0.f);
        ws[WS_FC + (n0 + r) * C + o] = a;
        s += a; ss = fmaf(a, a, ss);
    }
    atomicAdd(&red[0][o], s);
    atomicAdd(&red[1][o], ss);
    __syncthreads();
    if (t < C) {
        ws[WS_BN4P + b * 64 + t] = red[0][t];
        ws[WS_BN4P + b * 64 + 32 + t] = red[1][t];
    }
}

// ============================================================
// K6b: bn4 scale/shift.
// ============================================================
__global__ __launch_bounds__(64) void k6b_bn4(
    const float* __restrict__ g4, const float* __restrict__ bb4,
    float* __restrict__ ws)
{
    const int t = threadIdx.x;
    if (t < C) {
        float s = 0.f, q = 0.f;
        for (int b = 0; b < 16; ++b) {
            s += ws[WS_BN4P + b * 64 + t];
            q += ws[WS_BN4P + b * 64 + 32 + t];
        }
        const float m = s / 1024.f;
        const float v = q / 1024.f - m * m;
        const float scale = g4[t] / sqrtf(v + EPS);
        ws[WS_SC4 + t] = scale;
        ws[WS_SH4 + t] = bb4[t] - m * scale;
    }
}

// ============================================================
// K7: bn4 affine + x1 = A^T f4 + out = [f4,x1] @ gcn_w^T + gcn_b.
// ============================================================
__global__ __launch_bounds__(256) void k7_gcn(
    const float* __restrict__ A, const float* __restrict__ gw,
    const float* __restrict__ gb, const float* __restrict__ ws,
    float* __restrict__ out)
{
    __shared__ float As[8][64];
    __shared__ float fs[8][C];
    __shared__ float gws[C][65];
    __shared__ float f4s[64][C];
    __shared__ float x1s[64][C];
    const int t = threadIdx.x;
    const int w0 = blockIdx.x * 64;
    const int c = t & 31, wg = t >> 5;
    const float scC = ws[WS_SC4 + c], shC = ws[WS_SH4 + c];
    for (int idx = t; idx < 2048; idx += 256) gws[idx >> 6][idx & 63] = gw[idx];
    for (int idx = t; idx < 2048; idx += 256) {
        const int r = idx >> 5;
        f4s[r][c] = fmaf(ws[WS_FC + (w0 + r) * C + c], scC, shC);
    }
    float acc[8] = {0, 0, 0, 0, 0, 0, 0, 0};
    for (int v0 = 0; v0 < NB; v0 += 8) {
        __syncthreads();
        {
            const int vv = t >> 6, wl = t & 63;
            As[vv][wl]     = A[(size_t)(v0 + vv) * NB + w0 + wl];
            As[vv + 4][wl] = A[(size_t)(v0 + vv + 4) * NB + w0 + wl];
        }
        {
            const int vv = t >> 5;
            fs[vv][c] = fmaf(ws[WS_FC + (v0 + vv) * C + c], scC, shC);
        }
        __syncthreads();
#pragma unroll
        for (int vv = 0; vv < 8; ++vv) {
            const float fv = fs[vv][c];
#pragma unroll
            for (int j = 0; j < 8; ++j)
                acc[j] = fmaf(As[vv][wg + 8 * j], fv, acc[j]);
        }
    }
    __syncthreads();
#pragma unroll
    for (int j = 0; j < 8; ++j) x1s[wg + 8 * j][c] = acc[j];
    __syncthreads();
    const float gbv = gb[c];
#pragma unroll
    for (int j = 0; j < 8; ++j) {
        const int wl = wg + 8 * j;
        float a = gbv;
#pragma unroll
        for (int cc = 0; cc < C; ++cc) {
            a = fmaf(gws[c][cc],      f4s[wl][cc], a);
            a = fmaf(gws[c][32 + cc], x1s[wl][cc], a);
        }
        out[(w0 + wl) * C + c] = a;
    }
}

// ============================================================
extern "C" void kernel_launch(void* const* d_in, const int* in_sizes, int n_in,
                              void* d_out, int out_size, void* d_ws, size_t ws_size,
                              hipStream_t stream)
{
    (void)in_sizes; (void)n_in; (void)out_size;
    const float* x    = (const float*)d_in[0];
    const int*   perm = (const int*)  d_in[1];
    const float* A    = (const float*)d_in[2];
    const float* c1w  = (const float*)d_in[3];
    const float* c1b  = (const float*)d_in[4];
    const float* c2w  = (const float*)d_in[5];
    const float* c2b  = (const float*)d_in[6];
    const float* c3w  = (const float*)d_in[7];
    const float* c3b  = (const float*)d_in[8];
    const float* g1   = (const float*)d_in[9];
    const float* bb1  = (const float*)d_in[10];
    const float* g2   = (const float*)d_in[11];
    const float* bb2  = (const float*)d_in[12];
    const float* g3   = (const float*)d_in[13];
    const float* bb3  = (const float*)d_in[14];
    const float* g4   = (const float*)d_in[15];
    const float* bb4  = (const float*)d_in[16];
    const float* fw   = (const float*)d_in[17];
    const float* fb   = (const float*)d_in[18];
    const float* gw   = (const float*)d_in[19];
    const float* gb   = (const float*)d_in[20];
    float* ws  = (float*)d_ws;
    float* out = (float*)d_out;

    if (ws_size < WS_TOTALF * sizeof(float)) return;

    hipMemsetAsync(d_ws, 0, WS_ZEROF * sizeof(float), stream);
    k1_conv1_stats<<<dim3(NB), dim3(256), 0, stream>>>(x, c1w, c1b, ws);
    k2_fold_bn1  <<<dim3(1),  dim3(256), 0, stream>>>(c2w, c2b, g1, bb1, ws);
    k3_conv12    <<<dim3(21, NB), dim3(256), 0, stream>>>(x, c1w, c1b, ws);
    k4_fold_bn2  <<<dim3(1),  dim3(256), 0, stream>>>(c3w, c3b, g2, bb2, ws);
    k5_conv3_pool<<<dim3(NB), dim3(256), 0, stream>>>(perm, ws);
    k5b_bn3      <<<dim3(1),  dim3(128), 0, stream>>>(g3, bb3, ws);
    k6_fc1       <<<dim3(16), dim3(256), 0, stream>>>(fw, fb, ws);
    k6b_bn4      <<<dim3(1),  dim3(64),  0, stream>>>(g4, bb4, ws);
    k7_gcn       <<<dim3(16), dim3(256), 0, stream>>>(A, gw, gb, ws, out);
}